// Round 3
// baseline (987.590 us; speedup 1.0000x reference)
//
#include <hip/hip_runtime.h>

#define FEAT 18432

__device__ __forceinline__ float b2f(unsigned short s) {
  union { unsigned int u; float f; } v; v.u = ((unsigned int)s) << 16; return v.f;
}
__device__ __forceinline__ unsigned short f2bf(float x) {
  union { float f; unsigned int u; } v; v.f = x;
  unsigned int u = v.u;
  unsigned int r = (u + 0x7FFFu + ((u >> 16) & 1u)) >> 16;
  return (unsigned short)r;
}

// K0: s1[b][c][96][96] (f32) -> xT[b][patch=gh*8+gw][f=(p1*12+p2)*128+c] (bf16 staging)
__global__ __launch_bounds__(256) void k_transpose(const float* __restrict__ s1,
                                                   unsigned short* __restrict__ xT) {
  int H = blockIdx.x, b = blockIdx.y;
  int gh = H / 12, p1 = H % 12;
  __shared__ float lds[128][97];
  const float* src = s1 + ((size_t)b * 128) * 9216 + (size_t)H * 96;
  for (int idx = threadIdx.x; idx < 12288; idx += 256) {
    int c = idx / 96, w = idx - c * 96;
    lds[c][w] = src[(size_t)c * 9216 + w];
  }
  __syncthreads();
  unsigned short* dst = xT + (size_t)b * 64 * FEAT + (size_t)(gh * 8) * FEAT + (p1 * 12) * 128;
  for (int idx = threadIdx.x; idx < 6144; idx += 256) {
    int c2 = idx & 63, rem = idx >> 6;      // rem = gw*12+p2 in [0,96)
    unsigned int lo = f2bf(lds[c2 * 2][rem]);
    unsigned int hi = f2bf(lds[c2 * 2 + 1][rem]);
    int gw = rem / 12, p2 = rem - gw * 12;
    *(unsigned int*)(dst + (size_t)gw * FEAT + p2 * 128 + c2 * 2) = lo | (hi << 16);
  }
}

// K1: conv1d over f (64->64 patch channels, K=5, pad=2) + BN(eval) + ReLU + selective square
__global__ __launch_bounds__(256) void k_conv_pe(
    const unsigned short* __restrict__ xT, const float* __restrict__ pe_w,
    const float* __restrict__ bn_g, const float* __restrict__ bn_b,
    const float* __restrict__ bn_m, const float* __restrict__ bn_v,
    const int* __restrict__ indexp, unsigned short* __restrict__ ym) {
  int pix = blockIdx.x, b = blockIdx.y;
  int f0 = pix << 7;
  extern __shared__ float lds[];
  float* xl = lds;                 // [64][132]  f0-2 .. f0+129
  float* wl = lds + 64 * 132;      // [80][65]   (ic_local*5+kk)[oc], pad 65
  int t = threadIdx.x;
  int oc = t & 63, g = t >> 6;
  const unsigned short* xb = xT + (size_t)b * 64 * FEAT;
  for (int idx = t; idx < 8448; idx += 256) {
    int ic = idx / 132, j = idx - ic * 132;
    int f = f0 + j - 2;
    xl[idx] = (f >= 0 && f < FEAT) ? b2f(xb[(size_t)ic * FEAT + f]) : 0.f;
  }
  float acc[32];
#pragma unroll
  for (int i = 0; i < 32; ++i) acc[i] = 0.f;
  for (int ch = 0; ch < 4; ++ch) {
    __syncthreads();
    for (int idx = t; idx < 5120; idx += 256) {
      int r = idx % 80, o_ = idx / 80;
      wl[r * 65 + o_] = pe_w[o_ * 320 + ch * 80 + r];
    }
    __syncthreads();
#pragma unroll 1
    for (int icl = 0; icl < 16; ++icl) {
      int ic = (ch << 4) + icl;
      const float* wr = wl + icl * 5 * 65 + oc;
      float w0 = wr[0], w1 = wr[65], w2 = wr[130], w3 = wr[195], w4 = wr[260];
      float xw[36];
      const float4* xr = (const float4*)(xl + ic * 132 + (g << 5));
#pragma unroll
      for (int q = 0; q < 9; ++q) {
        float4 vv = xr[q];
        xw[q * 4] = vv.x; xw[q * 4 + 1] = vv.y; xw[q * 4 + 2] = vv.z; xw[q * 4 + 3] = vv.w;
      }
#pragma unroll
      for (int i = 0; i < 32; ++i)
        acc[i] = fmaf(xw[i], w0, fmaf(xw[i + 1], w1, fmaf(xw[i + 2], w2,
                 fmaf(xw[i + 3], w3, fmaf(xw[i + 4], w4, acc[i])))));
    }
  }
  float sc = bn_g[oc] * rsqrtf(bn_v[oc] + 1e-5f);
  float sh = bn_b[oc] - bn_m[oc] * sc;
  int i0 = indexp[0] / 12 * 8 + indexp[1] / 12;
  int i1 = indexp[2] / 12 * 8 + indexp[3] / 12;
  int i2 = indexp[4] / 12 * 8 + indexp[5] / 12;
  int i3 = indexp[6] / 12 * 8 + indexp[7] / 12;
  bool sel = (oc == i0) || (oc == i1) || (oc == i2) || (oc == i3);
  unsigned short* yo = ym + ((size_t)b * 64 + oc) * FEAT + f0 + (g << 5);
#pragma unroll
  for (int i = 0; i < 32; ++i) {
    float y = fmaf(acc[i], sc, sh);
    y = fmaxf(y, 0.f);
    if (!sel) y *= y;
    yo[i] = f2bf(y);
  }
}

// K2: 3x3 avg pool 96->32 in patch layout -> ori[b][n][c] (f32)
__global__ __launch_bounds__(256) void k_pool9(const unsigned short* __restrict__ ym,
                                               float* __restrict__ ori) {
  int oc = blockIdx.x, b = blockIdx.y;
  const unsigned short* src = ym + ((size_t)b * 64 + oc) * FEAT;
  int oh0 = (oc >> 3) << 2, ow0 = (oc & 7) << 2;
  for (int idx = threadIdx.x; idx < 2048; idx += 256) {
    int c = idx & 127, nl = idx >> 7;
    int pg1 = nl >> 2, pg2 = nl & 3;
    int pbase = (pg1 * 36 + pg2 * 3) * 128 + c;
    float s = 0.f;
#pragma unroll
    for (int dy = 0; dy < 3; ++dy)
#pragma unroll
      for (int dx = 0; dx < 3; ++dx)
        s += b2f(src[pbase + (dy * 12 + dx) * 128]);
    int n = (oh0 + pg1) * 32 + ow0 + pg2;
    ori[((size_t)b * 1024 + n) * 128 + c] = s * (1.f / 9.f);
  }
}

// K3: 2x2 avg pool of o (f32, 64->32) + LayerNorm over C -> ofl[b][n][c]
__global__ __launch_bounds__(256) void k_poolo_ln(
    const float* __restrict__ o, const float* __restrict__ lng,
    const float* __restrict__ lnb, float* __restrict__ ofl) {
  int y = blockIdx.x, b = blockIdx.y;
  __shared__ float pl[128 * 33];
  int t = threadIdx.x;
  for (int idx = t; idx < 4096; idx += 256) {
    int xo = idx & 31, c = idx >> 5;
    const float* p = o + (((size_t)b * 128 + c) * 64 + 2 * y) * 64 + 2 * xo;
    float2 a = *(const float2*)p;
    float2 d = *(const float2*)(p + 64);
    pl[c * 33 + xo] = 0.25f * (a.x + a.y + d.x + d.y);
  }
  __syncthreads();
  int xo = t >> 3, l8 = t & 7;
  float v[16]; float s = 0.f, q = 0.f;
#pragma unroll
  for (int i = 0; i < 16; ++i) {
    float x = pl[(l8 * 16 + i) * 33 + xo];
    v[i] = x; s += x; q += x * x;
  }
#pragma unroll
  for (int off = 1; off < 8; off <<= 1) {
    s += __shfl_xor(s, off, 8);
    q += __shfl_xor(q, off, 8);
  }
  float mean = s * (1.f / 128.f);
  float var = q * (1.f / 128.f) - mean * mean;
  float inv = rsqrtf(var + 1e-5f);
  float* dst = ofl + ((size_t)b * 1024 + y * 32 + xo) * 128 + l8 * 16;
#pragma unroll
  for (int i = 0; i < 16; ++i)
    dst[i] = (v[i] - mean) * inv * lng[l8 * 16 + i] + lnb[l8 * 16 + i];
}

// K4: LayerNorm over C of ori -> sn
__global__ __launch_bounds__(128) void k_ln(
    const float* __restrict__ src, const float* __restrict__ lng,
    const float* __restrict__ lnb, float* __restrict__ dst) {
  int n = blockIdx.x, b = blockIdx.y;
  size_t base = ((size_t)b * 1024 + n) * 128;
  int c = threadIdx.x;
  float v = src[base + c];
  float s = v, q = v * v;
#pragma unroll
  for (int off = 32; off > 0; off >>= 1) {
    s += __shfl_xor(s, off, 64);
    q += __shfl_xor(q, off, 64);
  }
  __shared__ float red[4];
  if ((c & 63) == 0) { red[(c >> 6) * 2] = s; red[(c >> 6) * 2 + 1] = q; }
  __syncthreads();
  s = red[0] + red[2]; q = red[1] + red[3];
  float mean = s * (1.f / 128.f);
  float var = q * (1.f / 128.f) - mean * mean;
  float inv = rsqrtf(var + 1e-5f);
  dst[base + c] = (v - mean) * inv * lng[c] + lnb[c];
}

// K5: out[M][Ncols] = A[M][128] @ W[Ncols][128]^T + bias
__global__ __launch_bounds__(256) void k_gemm(
    const float* __restrict__ A, const float* __restrict__ W,
    const float* __restrict__ bias, float* __restrict__ out, int Ncols) {
  int mt = blockIdx.x, ct = blockIdx.y;
  int m0 = mt << 6, c0 = ct << 6;
  __shared__ float Al[64 * 67], Wl[64 * 67];
  int t = threadIdx.x, tm = t & 15, tc = t >> 4;
  float acc[4][4];
#pragma unroll
  for (int i = 0; i < 4; ++i)
#pragma unroll
    for (int j = 0; j < 4; ++j) acc[i][j] = 0.f;
  for (int kc = 0; kc < 2; ++kc) {
    __syncthreads();
    for (int idx = t; idx < 4096; idx += 256) {
      int r = idx >> 6, kk = idx & 63;
      Al[r * 67 + kk] = A[(size_t)(m0 + r) * 128 + kc * 64 + kk];
      Wl[r * 67 + kk] = W[(size_t)(c0 + r) * 128 + kc * 64 + kk];
    }
    __syncthreads();
    for (int kk = 0; kk < 64; ++kk) {
      float a[4], w[4];
#pragma unroll
      for (int i = 0; i < 4; ++i) a[i] = Al[(tm * 4 + i) * 67 + kk];
#pragma unroll
      for (int j = 0; j < 4; ++j) w[j] = Wl[(tc * 4 + j) * 67 + kk];
#pragma unroll
      for (int i = 0; i < 4; ++i)
#pragma unroll
        for (int j = 0; j < 4; ++j) acc[i][j] = fmaf(a[i], w[j], acc[i][j]);
    }
  }
#pragma unroll
  for (int i = 0; i < 4; ++i) {
    float4 vv;
    vv.x = acc[i][0] + bias[c0 + tc * 4 + 0];
    vv.y = acc[i][1] + bias[c0 + tc * 4 + 1];
    vv.z = acc[i][2] + bias[c0 + tc * 4 + 2];
    vv.w = acc[i][3] + bias[c0 + tc * 4 + 3];
    *(float4*)(out + (size_t)(m0 + tm * 4 + i) * Ncols + c0 + tc * 4) = vv;
  }
}

// K6: flash-style attention per (b,h,q-tile of 64): att = v + softmax(qk^T/sqrt(32)) @ yv
__global__ __launch_bounds__(256) void k_attn(const float* __restrict__ qkv,
                                              const float* __restrict__ yvb,
                                              float* __restrict__ att) {
  int qt = blockIdx.x, h = blockIdx.y, b = blockIdx.z;
  __shared__ float Qs[64 * 33], Ks[64 * 33], Vs[64 * 33], Ps[64 * 65];
  int t = threadIdx.x, tx = t & 15, ty = t >> 4;
  const float* qbase = qkv + (size_t)b * 1024 * 384;
  for (int idx = t; idx < 2048; idx += 256) {
    int d = idx & 31, r2 = idx >> 5;
    Qs[r2 * 33 + d] = qbase[(size_t)(qt * 64 + r2) * 384 + h * 32 + d];
  }
  float O0[4], O1[4], mi[4], li[4];
#pragma unroll
  for (int i = 0; i < 4; ++i) { O0[i] = 0.f; O1[i] = 0.f; mi[i] = -1e30f; li[i] = 0.f; }
  __syncthreads();
  for (int mt = 0; mt < 16; ++mt) {
    int m0 = mt << 6;
    for (int idx = t; idx < 2048; idx += 256) {
      int d = idx & 31, r2 = idx >> 5;
      Ks[r2 * 33 + d] = qbase[(size_t)(m0 + r2) * 384 + 128 + h * 32 + d];
      Vs[r2 * 33 + d] = yvb[((size_t)b * 1024 + m0 + r2) * 128 + h * 32 + d];
    }
    __syncthreads();
    float s[4][4];
#pragma unroll
    for (int i = 0; i < 4; ++i)
#pragma unroll
      for (int j = 0; j < 4; ++j) s[i][j] = 0.f;
    for (int kd = 0; kd < 32; ++kd) {
      float qr[4], kr[4];
#pragma unroll
      for (int i = 0; i < 4; ++i) qr[i] = Qs[(ty * 4 + i) * 33 + kd];
#pragma unroll
      for (int j = 0; j < 4; ++j) kr[j] = Ks[(tx * 4 + j) * 33 + kd];
#pragma unroll
      for (int i = 0; i < 4; ++i)
#pragma unroll
        for (int j = 0; j < 4; ++j) s[i][j] = fmaf(qr[i], kr[j], s[i][j]);
    }
    const float scl = 0.17677669529663688f;
#pragma unroll
    for (int i = 0; i < 4; ++i) {
      float s0 = s[i][0] * scl, s1 = s[i][1] * scl, s2 = s[i][2] * scl, s3 = s[i][3] * scl;
      float rm = fmaxf(fmaxf(s0, s1), fmaxf(s2, s3));
      rm = fmaxf(rm, __shfl_xor(rm, 1, 16));
      rm = fmaxf(rm, __shfl_xor(rm, 2, 16));
      rm = fmaxf(rm, __shfl_xor(rm, 4, 16));
      rm = fmaxf(rm, __shfl_xor(rm, 8, 16));
      float nm = fmaxf(mi[i], rm);
      float alpha = __expf(mi[i] - nm);
      float p0 = __expf(s0 - nm), p1 = __expf(s1 - nm);
      float p2 = __expf(s2 - nm), p3 = __expf(s3 - nm);
      float ps = p0 + p1 + p2 + p3;
      ps += __shfl_xor(ps, 1, 16);
      ps += __shfl_xor(ps, 2, 16);
      ps += __shfl_xor(ps, 4, 16);
      ps += __shfl_xor(ps, 8, 16);
      li[i] = li[i] * alpha + ps;
      mi[i] = nm;
      O0[i] *= alpha; O1[i] *= alpha;
      int pr = (ty * 4 + i) * 65 + tx * 4;
      Ps[pr] = p0; Ps[pr + 1] = p1; Ps[pr + 2] = p2; Ps[pr + 3] = p3;
    }
    __syncthreads();
    for (int m = 0; m < 64; ++m) {
      float v0 = Vs[m * 33 + tx * 2], v1 = Vs[m * 33 + tx * 2 + 1];
#pragma unroll
      for (int i = 0; i < 4; ++i) {
        float p = Ps[(ty * 4 + i) * 65 + m];
        O0[i] = fmaf(p, v0, O0[i]);
        O1[i] = fmaf(p, v1, O1[i]);
      }
    }
    __syncthreads();
  }
#pragma unroll
  for (int i = 0; i < 4; ++i) {
    int n = qt * 64 + ty * 4 + i;
    float inv = 1.f / li[i];
    int d0 = h * 32 + tx * 2;
    float va = qbase[(size_t)n * 384 + 256 + d0];
    float vb = qbase[(size_t)n * 384 + 256 + d0 + 1];
    float* op = att + ((size_t)b * 1024 + n) * 128 + d0;
    op[0] = O0[i] * inv + va;
    op[1] = O1[i] * inv + vb;
  }
}

// K7: proj GEMM + bias + ori residual, write transposed xv2[b][c][n]
__global__ __launch_bounds__(256) void k_proj(
    const float* __restrict__ att, const float* __restrict__ proj_w,
    const float* __restrict__ proj_b, const float* __restrict__ ori,
    float* __restrict__ xv2) {
  int nt = blockIdx.x, b = blockIdx.y;
  int n0 = nt << 6;
  __shared__ float Al[64 * 67], Wl[128 * 67];
  int t = threadIdx.x, tn = t & 15, tc = t >> 4;
  float acc[4][8];
#pragma unroll
  for (int i = 0; i < 4; ++i)
#pragma unroll
    for (int j = 0; j < 8; ++j) acc[i][j] = 0.f;
  const float* Ab = att + ((size_t)b * 1024 + n0) * 128;
  for (int kc = 0; kc < 2; ++kc) {
    __syncthreads();
    for (int idx = t; idx < 4096; idx += 256) {
      int r = idx >> 6, kk = idx & 63;
      Al[r * 67 + kk] = Ab[(size_t)r * 128 + kc * 64 + kk];
    }
    for (int idx = t; idx < 8192; idx += 256) {
      int r = idx >> 6, kk = idx & 63;
      Wl[r * 67 + kk] = proj_w[(size_t)r * 128 + kc * 64 + kk];
    }
    __syncthreads();
    for (int kk = 0; kk < 64; ++kk) {
      float a[4], w[8];
#pragma unroll
      for (int i = 0; i < 4; ++i) a[i] = Al[(tn * 4 + i) * 67 + kk];
#pragma unroll
      for (int j = 0; j < 8; ++j) w[j] = Wl[(tc * 8 + j) * 67 + kk];
#pragma unroll
      for (int i = 0; i < 4; ++i)
#pragma unroll
        for (int j = 0; j < 8; ++j) acc[i][j] = fmaf(a[i], w[j], acc[i][j]);
    }
  }
#pragma unroll
  for (int j = 0; j < 8; ++j) {
    int c = tc * 8 + j;
    float pb = proj_b[c];
    float4 vv;
    vv.x = acc[0][j] + pb + ori[((size_t)b * 1024 + n0 + tn * 4 + 0) * 128 + c];
    vv.y = acc[1][j] + pb + ori[((size_t)b * 1024 + n0 + tn * 4 + 1) * 128 + c];
    vv.z = acc[2][j] + pb + ori[((size_t)b * 1024 + n0 + tn * 4 + 2) * 128 + c];
    vv.w = acc[3][j] + pb + ori[((size_t)b * 1024 + n0 + tn * 4 + 3) * 128 + c];
    *(float4*)(xv2 + ((size_t)b * 128 + c) * 1024 + n0 + tn * 4) = vv;
  }
}

// K8: conv1d over n (128->128 channels, K=5, pad=2) + residual
__global__ __launch_bounds__(256) void k_conv1d(
    const float* __restrict__ xv2, const float* __restrict__ cw,
    float* __restrict__ xv3) {
  int nt = blockIdx.x, b = blockIdx.y;
  int n0 = nt << 6;
  extern __shared__ float lds[];
  float* xl = lds;                 // [128][68]
  float* wl = lds + 128 * 68;      // [40][129]
  int t = threadIdx.x, oc = t & 127, g = t >> 7;
  const float* xb = xv2 + (size_t)b * 128 * 1024;
  for (int idx = t; idx < 8704; idx += 256) {
    int ic = idx / 68, j = idx - ic * 68;
    int n = n0 + j - 2;
    xl[idx] = (n >= 0 && n < 1024) ? xb[(size_t)ic * 1024 + n] : 0.f;
  }
  float acc[32];
#pragma unroll
  for (int i = 0; i < 32; ++i) acc[i] = 0.f;
  for (int ch = 0; ch < 16; ++ch) {
    __syncthreads();
    for (int idx = t; idx < 5120; idx += 256) {
      int r = idx % 40, o_ = idx / 40;
      wl[r * 129 + o_] = cw[o_ * 640 + ch * 40 + r];
    }
    __syncthreads();
#pragma unroll 1
    for (int icl = 0; icl < 8; ++icl) {
      int ic = (ch << 3) + icl;
      const float* wr = wl + icl * 5 * 129 + oc;
      float w0 = wr[0], w1 = wr[129], w2 = wr[258], w3 = wr[387], w4 = wr[516];
      float xw[36];
      const float4* xr = (const float4*)(xl + ic * 68 + (g << 5));
#pragma unroll
      for (int q2 = 0; q2 < 9; ++q2) {
        float4 vv = xr[q2];
        xw[q2 * 4] = vv.x; xw[q2 * 4 + 1] = vv.y; xw[q2 * 4 + 2] = vv.z; xw[q2 * 4 + 3] = vv.w;
      }
#pragma unroll
      for (int i = 0; i < 32; ++i)
        acc[i] = fmaf(xw[i], w0, fmaf(xw[i + 1], w1, fmaf(xw[i + 2], w2,
                 fmaf(xw[i + 3], w3, fmaf(xw[i + 4], w4, acc[i])))));
    }
  }
  const float* res = xb + (size_t)oc * 1024 + n0 + (g << 5);
  float* outp = xv3 + ((size_t)b * 128 + oc) * 1024 + n0 + (g << 5);
#pragma unroll
  for (int i = 0; i < 32; ++i) outp[i] = res[i] + acc[i];
}

// K9: bilinear 32->96 align_corners=True, f32 out
__global__ __launch_bounds__(256) void k_bilinear(const float* __restrict__ xv3,
                                                  float* __restrict__ out) {
  int idx = blockIdx.x * 256 + threadIdx.x;
  int X = idx % 96;
  int t2 = idx / 96;
  int Y = t2 % 96;
  int bc = t2 / 96;
  const float* src = xv3 + (size_t)bc * 1024;
  const float r = 31.f / 95.f;
  float py = Y * r, px = X * r;
  int y0 = (int)py, x0 = (int)px;
  float wy = py - y0, wx = px - x0;
  int y1 = y0 < 31 ? y0 + 1 : 31, x1 = x0 < 31 ? x0 + 1 : 31;
  float a = src[y0 * 32 + x0], b_ = src[y0 * 32 + x1];
  float c_ = src[y1 * 32 + x0], d_ = src[y1 * 32 + x1];
  float t0 = a * (1.f - wy) + c_ * wy;
  float t1 = b_ * (1.f - wy) + d_ * wy;
  out[idx] = t0 * (1.f - wx) + t1 * wx;
}

extern "C" void kernel_launch(void* const* d_in, const int* in_sizes, int n_in,
                              void* d_out, int out_size, void* d_ws, size_t ws_size,
                              hipStream_t stream) {
  (void)in_sizes; (void)n_in; (void)out_size; (void)ws_size;
  const float* s1    = (const float*)d_in[0];
  const float* o     = (const float*)d_in[1];
  const int*   indx  = (const int*)d_in[2];
  const float* pe_w  = (const float*)d_in[3];
  const float* bn_g  = (const float*)d_in[4];
  const float* bn_b  = (const float*)d_in[5];
  const float* bn_m  = (const float*)d_in[6];
  const float* bn_v  = (const float*)d_in[7];
  const float* lnx_g = (const float*)d_in[8];
  const float* lnx_b = (const float*)d_in[9];
  const float* lny_g = (const float*)d_in[10];
  const float* lny_b = (const float*)d_in[11];
  const float* qkv_w = (const float*)d_in[12];
  const float* qkv_b = (const float*)d_in[13];
  const float* yv_w  = (const float*)d_in[14];
  const float* yv_b  = (const float*)d_in[15];
  const float* proj_w = (const float*)d_in[16];
  const float* proj_b = (const float*)d_in[17];
  const float* c1d_w  = (const float*)d_in[18];

  char* ws = (char*)d_ws;
  // Peak footprint 75,497,472 B:
  // Phase 1: xTh bf16 [ws+0, 37.7MB), ymh bf16 [ws+37.7MB, 75.5MB).
  unsigned short* xTh = (unsigned short*)ws;
  unsigned short* ymh = (unsigned short*)(ws + 37748736);
  // Phase 2 (xTh dead after k_conv_pe): region A = [ws+0, 37.7MB)
  float* ori  = (float*)ws;
  float* sn   = (float*)(ws + 8388608);
  float* ofl  = (float*)(ws + 16777216);
  float* attb = (float*)(ws + 25165824);
  // Phase 3 (ymh dead after k_pool9): region B = [ws+37.7MB, 75.5MB)
  float* qkvb  = (float*)(ws + 37748736);
  float* yvbuf = (float*)(ws + 62914560);
  float* xv2   = (float*)(ws + 37748736);   // alias qkvb (dead after k_attn)
  float* xv3   = (float*)(ws + 46137344);

  hipLaunchKernelGGL(k_transpose, dim3(96, 16), dim3(256), 0, stream, s1, xTh);
  hipLaunchKernelGGL(k_conv_pe, dim3(144, 16), dim3(256), 54592, stream,
                     xTh, pe_w, bn_g, bn_b, bn_m, bn_v, indx, ymh);
  hipLaunchKernelGGL(k_pool9, dim3(64, 16), dim3(256), 0, stream, ymh, ori);
  hipLaunchKernelGGL(k_poolo_ln, dim3(32, 16), dim3(256), 0, stream, o, lnx_g, lnx_b, ofl);
  hipLaunchKernelGGL(k_ln, dim3(1024, 16), dim3(128), 0, stream, ori, lny_g, lny_b, sn);
  hipLaunchKernelGGL(k_gemm, dim3(256, 6), dim3(256), 0, stream, ofl, qkv_w, qkv_b, qkvb, 384);
  hipLaunchKernelGGL(k_gemm, dim3(256, 2), dim3(256), 0, stream, sn, yv_w, yv_b, yvbuf, 128);
  hipLaunchKernelGGL(k_attn, dim3(16, 4, 16), dim3(256), 0, stream, qkvb, yvbuf, attb);
  hipLaunchKernelGGL(k_proj, dim3(16, 16), dim3(256), 0, stream, attb, proj_w, proj_b, ori, xv2);
  hipLaunchKernelGGL(k_conv1d, dim3(16, 16), dim3(256), 55456, stream, xv2, c1d_w, xv3);
  hipLaunchKernelGGL(k_bilinear, dim3(73728), dim3(256), 0, stream, xv3, (float*)d_out);
}

// Round 4
// 840.807 us; speedup vs baseline: 1.1746x; 1.1746x over previous
//
#include <hip/hip_runtime.h>

#define FEAT 18432

typedef __attribute__((ext_vector_type(8))) short short8;
typedef __attribute__((ext_vector_type(4))) float f32x4;

__device__ __forceinline__ float b2f(unsigned short s) {
  union { unsigned int u; float f; } v; v.u = ((unsigned int)s) << 16; return v.f;
}
__device__ __forceinline__ unsigned short f2bf(float x) {
  union { float f; unsigned int u; } v; v.f = x;
  unsigned int u = v.u;
  unsigned int r = (u + 0x7FFFu + ((u >> 16) & 1u)) >> 16;
  return (unsigned short)r;
}

// K0: s1[b][c][96][96] (f32) -> xT[b][patch=gh*8+gw][f=(p1*12+p2)*128+c] (bf16 staging)
__global__ __launch_bounds__(256) void k_transpose(const float* __restrict__ s1,
                                                   unsigned short* __restrict__ xT) {
  int H = blockIdx.x, b = blockIdx.y;
  int gh = H / 12, p1 = H % 12;
  __shared__ float lds[128][97];
  const float* src = s1 + ((size_t)b * 128) * 9216 + (size_t)H * 96;
  for (int idx = threadIdx.x; idx < 12288; idx += 256) {
    int c = idx / 96, w = idx - c * 96;
    lds[c][w] = src[(size_t)c * 9216 + w];
  }
  __syncthreads();
  unsigned short* dst = xT + (size_t)b * 64 * FEAT + (size_t)(gh * 8) * FEAT + (p1 * 12) * 128;
  for (int idx = threadIdx.x; idx < 6144; idx += 256) {
    int c2 = idx & 63, rem = idx >> 6;      // rem = gw*12+p2 in [0,96)
    unsigned int lo = f2bf(lds[c2 * 2][rem]);
    unsigned int hi = f2bf(lds[c2 * 2 + 1][rem]);
    int gw = rem / 12, p2 = rem - gw * 12;
    *(unsigned int*)(dst + (size_t)gw * FEAT + p2 * 128 + c2 * 2) = lo | (hi << 16);
  }
}

// K1 (MFMA): conv1d over f as GEMM M=64(oc) x N=18432(f) x K=320(kk*64+ic)
// + BN(eval) + ReLU + selective square. 16x16x32 bf16 MFMA.
// LDS: Wl[64][328 pad] bf16 | x_lds[260][72 pad] bf16 | sc/sh/sel[64]
__global__ __launch_bounds__(256) void k_conv_pe(
    const unsigned short* __restrict__ xT, const float* __restrict__ pe_w,
    const float* __restrict__ bn_g, const float* __restrict__ bn_b,
    const float* __restrict__ bn_m, const float* __restrict__ bn_v,
    const int* __restrict__ indexp, unsigned short* __restrict__ ym) {
  extern __shared__ char smem[];
  unsigned short* Wl = (unsigned short*)smem;            // 64*328*2 = 41984 B
  unsigned short* xl = (unsigned short*)(smem + 41984);  // 260*72*2 = 37440 B
  float* scf = (float*)(smem + 79424);                   // 64 f32
  float* shf = (float*)(smem + 79680);                   // 64 f32
  int*   sli = (int*)(smem + 79936);                     // 64 int
  int t = threadIdx.x;
  int b = blockIdx.y;
  int blk_f0 = blockIdx.x << 9;                          // 512 f per block

  // pack weights: Wl[oc][kk*64+ic] = bf16(pe_w[oc][ic][kk])
  for (int idx = t; idx < 20480; idx += 256) {
    int oc = idx >> 5 >> 5;         // idx / 1024? no — compute directly:
    oc = idx / 320;
    int c = idx - oc * 320;
    int kk = c >> 6, ic = c & 63;
    Wl[oc * 328 + c] = f2bf(pe_w[(oc * 64 + ic) * 5 + kk]);
  }
  if (t < 64) {
    float sc = bn_g[t] * rsqrtf(bn_v[t] + 1e-5f);
    scf[t] = sc;
    shf[t] = bn_b[t] - bn_m[t] * sc;
    int i0 = indexp[0] / 12 * 8 + indexp[1] / 12;
    int i1 = indexp[2] / 12 * 8 + indexp[3] / 12;
    int i2 = indexp[4] / 12 * 8 + indexp[5] / 12;
    int i3 = indexp[6] / 12 * 8 + indexp[7] / 12;
    sli[t] = (t == i0 || t == i1 || t == i2 || t == i3) ? 1 : 0;
  }

  const unsigned short* xb = xT + (size_t)b * 64 * FEAT;
  int lane = t & 63, w = t >> 6;
  int n16 = lane & 15, q = lane >> 4;

  // per-lane LDS read bases (bf16 element units)
  int aB0 = n16 * 328 + q * 8;                 // + mt*16*328 + kk*64 + ih*32
  int bB0 = (w * 64 + n16) * 72 + q * 8;       // + nt*16*72 + kk*72 + ih*32

  for (int wnd = 0; wnd < 2; ++wnd) {
    int F0 = blk_f0 + (wnd << 8);
    __syncthreads();
    // stage x_lds[fl][ic] = x[ic][F0-2+fl], fl in [0,260)
    for (int idx = t; idx < 16640; idx += 256) {
      int ic = idx / 260, fl = idx - ic * 260;
      int f = F0 - 2 + fl;
      unsigned short v = 0;
      if (f >= 0 && f < FEAT) v = xb[(size_t)ic * FEAT + f];
      xl[fl * 72 + ic] = v;
    }
    __syncthreads();

    f32x4 acc[4][4];
#pragma unroll
    for (int mt = 0; mt < 4; ++mt)
#pragma unroll
      for (int nt = 0; nt < 4; ++nt) acc[mt][nt] = (f32x4){0.f, 0.f, 0.f, 0.f};

#pragma unroll
    for (int kk = 0; kk < 5; ++kk) {
#pragma unroll
      for (int ih = 0; ih < 2; ++ih) {
        int ao = kk * 64 + ih * 32;
        int bo = kk * 72 + ih * 32;
        short8 a0 = *(const short8*)(Wl + aB0 + ao);
        short8 a1 = *(const short8*)(Wl + aB0 + 16 * 328 + ao);
        short8 a2 = *(const short8*)(Wl + aB0 + 32 * 328 + ao);
        short8 a3 = *(const short8*)(Wl + aB0 + 48 * 328 + ao);
        short8 b0 = *(const short8*)(xl + bB0 + bo);
        short8 b1 = *(const short8*)(xl + bB0 + 16 * 72 + bo);
        short8 b2 = *(const short8*)(xl + bB0 + 32 * 72 + bo);
        short8 b3 = *(const short8*)(xl + bB0 + 48 * 72 + bo);
        acc[0][0] = __builtin_amdgcn_mfma_f32_16x16x32_bf16(a0, b0, acc[0][0], 0, 0, 0);
        acc[0][1] = __builtin_amdgcn_mfma_f32_16x16x32_bf16(a0, b1, acc[0][1], 0, 0, 0);
        acc[0][2] = __builtin_amdgcn_mfma_f32_16x16x32_bf16(a0, b2, acc[0][2], 0, 0, 0);
        acc[0][3] = __builtin_amdgcn_mfma_f32_16x16x32_bf16(a0, b3, acc[0][3], 0, 0, 0);
        acc[1][0] = __builtin_amdgcn_mfma_f32_16x16x32_bf16(a1, b0, acc[1][0], 0, 0, 0);
        acc[1][1] = __builtin_amdgcn_mfma_f32_16x16x32_bf16(a1, b1, acc[1][1], 0, 0, 0);
        acc[1][2] = __builtin_amdgcn_mfma_f32_16x16x32_bf16(a1, b2, acc[1][2], 0, 0, 0);
        acc[1][3] = __builtin_amdgcn_mfma_f32_16x16x32_bf16(a1, b3, acc[1][3], 0, 0, 0);
        acc[2][0] = __builtin_amdgcn_mfma_f32_16x16x32_bf16(a2, b0, acc[2][0], 0, 0, 0);
        acc[2][1] = __builtin_amdgcn_mfma_f32_16x16x32_bf16(a2, b1, acc[2][1], 0, 0, 0);
        acc[2][2] = __builtin_amdgcn_mfma_f32_16x16x32_bf16(a2, b2, acc[2][2], 0, 0, 0);
        acc[2][3] = __builtin_amdgcn_mfma_f32_16x16x32_bf16(a2, b3, acc[2][3], 0, 0, 0);
        acc[3][0] = __builtin_amdgcn_mfma_f32_16x16x32_bf16(a3, b0, acc[3][0], 0, 0, 0);
        acc[3][1] = __builtin_amdgcn_mfma_f32_16x16x32_bf16(a3, b1, acc[3][1], 0, 0, 0);
        acc[3][2] = __builtin_amdgcn_mfma_f32_16x16x32_bf16(a3, b2, acc[3][2], 0, 0, 0);
        acc[3][3] = __builtin_amdgcn_mfma_f32_16x16x32_bf16(a3, b3, acc[3][3], 0, 0, 0);
      }
    }

    // epilogue: D[row=q*4+i][col=n16] per tile; row->oc, col->f
#pragma unroll
    for (int mt = 0; mt < 4; ++mt) {
#pragma unroll
      for (int i = 0; i < 4; ++i) {
        int oc = mt * 16 + q * 4 + i;
        float sc = scf[oc], sh = shf[oc];
        bool sel = sli[oc] != 0;
        unsigned short* yo = ym + ((size_t)b * 64 + oc) * FEAT + F0 + w * 64 + n16;
#pragma unroll
        for (int nt = 0; nt < 4; ++nt) {
          float y = fmaf(acc[mt][nt][i], sc, sh);
          y = fmaxf(y, 0.f);
          if (!sel) y *= y;
          yo[nt * 16] = f2bf(y);
        }
      }
    }
  }
}

// K2: 3x3 avg pool 96->32 in patch layout -> ori[b][n][c] (f32)
__global__ __launch_bounds__(256) void k_pool9(const unsigned short* __restrict__ ym,
                                               float* __restrict__ ori) {
  int oc = blockIdx.x, b = blockIdx.y;
  const unsigned short* src = ym + ((size_t)b * 64 + oc) * FEAT;
  int oh0 = (oc >> 3) << 2, ow0 = (oc & 7) << 2;
  for (int idx = threadIdx.x; idx < 2048; idx += 256) {
    int c = idx & 127, nl = idx >> 7;
    int pg1 = nl >> 2, pg2 = nl & 3;
    int pbase = (pg1 * 36 + pg2 * 3) * 128 + c;
    float s = 0.f;
#pragma unroll
    for (int dy = 0; dy < 3; ++dy)
#pragma unroll
      for (int dx = 0; dx < 3; ++dx)
        s += b2f(src[pbase + (dy * 12 + dx) * 128]);
    int n = (oh0 + pg1) * 32 + ow0 + pg2;
    ori[((size_t)b * 1024 + n) * 128 + c] = s * (1.f / 9.f);
  }
}

// K3: 2x2 avg pool of o (f32, 64->32) + LayerNorm over C -> ofl[b][n][c]
__global__ __launch_bounds__(256) void k_poolo_ln(
    const float* __restrict__ o, const float* __restrict__ lng,
    const float* __restrict__ lnb, float* __restrict__ ofl) {
  int y = blockIdx.x, b = blockIdx.y;
  __shared__ float pl[128 * 33];
  int t = threadIdx.x;
  for (int idx = t; idx < 4096; idx += 256) {
    int xo = idx & 31, c = idx >> 5;
    const float* p = o + (((size_t)b * 128 + c) * 64 + 2 * y) * 64 + 2 * xo;
    float2 a = *(const float2*)p;
    float2 d = *(const float2*)(p + 64);
    pl[c * 33 + xo] = 0.25f * (a.x + a.y + d.x + d.y);
  }
  __syncthreads();
  int xo = t >> 3, l8 = t & 7;
  float v[16]; float s = 0.f, q = 0.f;
#pragma unroll
  for (int i = 0; i < 16; ++i) {
    float x = pl[(l8 * 16 + i) * 33 + xo];
    v[i] = x; s += x; q += x * x;
  }
#pragma unroll
  for (int off = 1; off < 8; off <<= 1) {
    s += __shfl_xor(s, off, 8);
    q += __shfl_xor(q, off, 8);
  }
  float mean = s * (1.f / 128.f);
  float var = q * (1.f / 128.f) - mean * mean;
  float inv = rsqrtf(var + 1e-5f);
  float* dst = ofl + ((size_t)b * 1024 + y * 32 + xo) * 128 + l8 * 16;
#pragma unroll
  for (int i = 0; i < 16; ++i)
    dst[i] = (v[i] - mean) * inv * lng[l8 * 16 + i] + lnb[l8 * 16 + i];
}

// K4: LayerNorm over C of ori -> sn
__global__ __launch_bounds__(128) void k_ln(
    const float* __restrict__ src, const float* __restrict__ lng,
    const float* __restrict__ lnb, float* __restrict__ dst) {
  int n = blockIdx.x, b = blockIdx.y;
  size_t base = ((size_t)b * 1024 + n) * 128;
  int c = threadIdx.x;
  float v = src[base + c];
  float s = v, q = v * v;
#pragma unroll
  for (int off = 32; off > 0; off >>= 1) {
    s += __shfl_xor(s, off, 64);
    q += __shfl_xor(q, off, 64);
  }
  __shared__ float red[4];
  if ((c & 63) == 0) { red[(c >> 6) * 2] = s; red[(c >> 6) * 2 + 1] = q; }
  __syncthreads();
  s = red[0] + red[2]; q = red[1] + red[3];
  float mean = s * (1.f / 128.f);
  float var = q * (1.f / 128.f) - mean * mean;
  float inv = rsqrtf(var + 1e-5f);
  dst[base + c] = (v - mean) * inv * lng[c] + lnb[c];
}

// K5: out[M][Ncols] = A[M][128] @ W[Ncols][128]^T + bias
__global__ __launch_bounds__(256) void k_gemm(
    const float* __restrict__ A, const float* __restrict__ W,
    const float* __restrict__ bias, float* __restrict__ out, int Ncols) {
  int mt = blockIdx.x, ct = blockIdx.y;
  int m0 = mt << 6, c0 = ct << 6;
  __shared__ float Al[64 * 67], Wl[64 * 67];
  int t = threadIdx.x, tm = t & 15, tc = t >> 4;
  float acc[4][4];
#pragma unroll
  for (int i = 0; i < 4; ++i)
#pragma unroll
    for (int j = 0; j < 4; ++j) acc[i][j] = 0.f;
  for (int kc = 0; kc < 2; ++kc) {
    __syncthreads();
    for (int idx = t; idx < 4096; idx += 256) {
      int r = idx >> 6, kk = idx & 63;
      Al[r * 67 + kk] = A[(size_t)(m0 + r) * 128 + kc * 64 + kk];
      Wl[r * 67 + kk] = W[(size_t)(c0 + r) * 128 + kc * 64 + kk];
    }
    __syncthreads();
    for (int kk = 0; kk < 64; ++kk) {
      float a[4], w[4];
#pragma unroll
      for (int i = 0; i < 4; ++i) a[i] = Al[(tm * 4 + i) * 67 + kk];
#pragma unroll
      for (int j = 0; j < 4; ++j) w[j] = Wl[(tc * 4 + j) * 67 + kk];
#pragma unroll
      for (int i = 0; i < 4; ++i)
#pragma unroll
        for (int j = 0; j < 4; ++j) acc[i][j] = fmaf(a[i], w[j], acc[i][j]);
    }
  }
#pragma unroll
  for (int i = 0; i < 4; ++i) {
    float4 vv;
    vv.x = acc[i][0] + bias[c0 + tc * 4 + 0];
    vv.y = acc[i][1] + bias[c0 + tc * 4 + 1];
    vv.z = acc[i][2] + bias[c0 + tc * 4 + 2];
    vv.w = acc[i][3] + bias[c0 + tc * 4 + 3];
    *(float4*)(out + (size_t)(m0 + tm * 4 + i) * Ncols + c0 + tc * 4) = vv;
  }
}

// K6: flash-style attention per (b,h,q-tile of 64): att = v + softmax(qk^T/sqrt(32)) @ yv
__global__ __launch_bounds__(256) void k_attn(const float* __restrict__ qkv,
                                              const float* __restrict__ yvb,
                                              float* __restrict__ att) {
  int qt = blockIdx.x, h = blockIdx.y, b = blockIdx.z;
  __shared__ float Qs[64 * 33], Ks[64 * 33], Vs[64 * 33], Ps[64 * 65];
  int t = threadIdx.x, tx = t & 15, ty = t >> 4;
  const float* qbase = qkv + (size_t)b * 1024 * 384;
  for (int idx = t; idx < 2048; idx += 256) {
    int d = idx & 31, r2 = idx >> 5;
    Qs[r2 * 33 + d] = qbase[(size_t)(qt * 64 + r2) * 384 + h * 32 + d];
  }
  float O0[4], O1[4], mi[4], li[4];
#pragma unroll
  for (int i = 0; i < 4; ++i) { O0[i] = 0.f; O1[i] = 0.f; mi[i] = -1e30f; li[i] = 0.f; }
  __syncthreads();
  for (int mt = 0; mt < 16; ++mt) {
    int m0 = mt << 6;
    for (int idx = t; idx < 2048; idx += 256) {
      int d = idx & 31, r2 = idx >> 5;
      Ks[r2 * 33 + d] = qbase[(size_t)(m0 + r2) * 384 + 128 + h * 32 + d];
      Vs[r2 * 33 + d] = yvb[((size_t)b * 1024 + m0 + r2) * 128 + h * 32 + d];
    }
    __syncthreads();
    float s[4][4];
#pragma unroll
    for (int i = 0; i < 4; ++i)
#pragma unroll
      for (int j = 0; j < 4; ++j) s[i][j] = 0.f;
    for (int kd = 0; kd < 32; ++kd) {
      float qr[4], kr[4];
#pragma unroll
      for (int i = 0; i < 4; ++i) qr[i] = Qs[(ty * 4 + i) * 33 + kd];
#pragma unroll
      for (int j = 0; j < 4; ++j) kr[j] = Ks[(tx * 4 + j) * 33 + kd];
#pragma unroll
      for (int i = 0; i < 4; ++i)
#pragma unroll
        for (int j = 0; j < 4; ++j) s[i][j] = fmaf(qr[i], kr[j], s[i][j]);
    }
    const float scl = 0.17677669529663688f;
#pragma unroll
    for (int i = 0; i < 4; ++i) {
      float s0 = s[i][0] * scl, s1 = s[i][1] * scl, s2 = s[i][2] * scl, s3 = s[i][3] * scl;
      float rm = fmaxf(fmaxf(s0, s1), fmaxf(s2, s3));
      rm = fmaxf(rm, __shfl_xor(rm, 1, 16));
      rm = fmaxf(rm, __shfl_xor(rm, 2, 16));
      rm = fmaxf(rm, __shfl_xor(rm, 4, 16));
      rm = fmaxf(rm, __shfl_xor(rm, 8, 16));
      float nm = fmaxf(mi[i], rm);
      float alpha = __expf(mi[i] - nm);
      float p0 = __expf(s0 - nm), p1 = __expf(s1 - nm);
      float p2 = __expf(s2 - nm), p3 = __expf(s3 - nm);
      float ps = p0 + p1 + p2 + p3;
      ps += __shfl_xor(ps, 1, 16);
      ps += __shfl_xor(ps, 2, 16);
      ps += __shfl_xor(ps, 4, 16);
      ps += __shfl_xor(ps, 8, 16);
      li[i] = li[i] * alpha + ps;
      mi[i] = nm;
      O0[i] *= alpha; O1[i] *= alpha;
      int pr = (ty * 4 + i) * 65 + tx * 4;
      Ps[pr] = p0; Ps[pr + 1] = p1; Ps[pr + 2] = p2; Ps[pr + 3] = p3;
    }
    __syncthreads();
    for (int m = 0; m < 64; ++m) {
      float v0 = Vs[m * 33 + tx * 2], v1 = Vs[m * 33 + tx * 2 + 1];
#pragma unroll
      for (int i = 0; i < 4; ++i) {
        float p = Ps[(ty * 4 + i) * 65 + m];
        O0[i] = fmaf(p, v0, O0[i]);
        O1[i] = fmaf(p, v1, O1[i]);
      }
    }
    __syncthreads();
  }
#pragma unroll
  for (int i = 0; i < 4; ++i) {
    int n = qt * 64 + ty * 4 + i;
    float inv = 1.f / li[i];
    int d0 = h * 32 + tx * 2;
    float va = qbase[(size_t)n * 384 + 256 + d0];
    float vb = qbase[(size_t)n * 384 + 256 + d0 + 1];
    float* op = att + ((size_t)b * 1024 + n) * 128 + d0;
    op[0] = O0[i] * inv + va;
    op[1] = O1[i] * inv + vb;
  }
}

// K7: proj GEMM + bias + ori residual, write transposed xv2[b][c][n]
__global__ __launch_bounds__(256) void k_proj(
    const float* __restrict__ att, const float* __restrict__ proj_w,
    const float* __restrict__ proj_b, const float* __restrict__ ori,
    float* __restrict__ xv2) {
  int nt = blockIdx.x, b = blockIdx.y;
  int n0 = nt << 6;
  __shared__ float Al[64 * 67], Wl[128 * 67];
  int t = threadIdx.x, tn = t & 15, tc = t >> 4;
  float acc[4][8];
#pragma unroll
  for (int i = 0; i < 4; ++i)
#pragma unroll
    for (int j = 0; j < 8; ++j) acc[i][j] = 0.f;
  const float* Ab = att + ((size_t)b * 1024 + n0) * 128;
  for (int kc = 0; kc < 2; ++kc) {
    __syncthreads();
    for (int idx = t; idx < 4096; idx += 256) {
      int r = idx >> 6, kk = idx & 63;
      Al[r * 67 + kk] = Ab[(size_t)r * 128 + kc * 64 + kk];
    }
    for (int idx = t; idx < 8192; idx += 256) {
      int r = idx >> 6, kk = idx & 63;
      Wl[r * 67 + kk] = proj_w[(size_t)r * 128 + kc * 64 + kk];
    }
    __syncthreads();
    for (int kk = 0; kk < 64; ++kk) {
      float a[4], w[8];
#pragma unroll
      for (int i = 0; i < 4; ++i) a[i] = Al[(tn * 4 + i) * 67 + kk];
#pragma unroll
      for (int j = 0; j < 8; ++j) w[j] = Wl[(tc * 8 + j) * 67 + kk];
#pragma unroll
      for (int i = 0; i < 4; ++i)
#pragma unroll
        for (int j = 0; j < 8; ++j) acc[i][j] = fmaf(a[i], w[j], acc[i][j]);
    }
  }
#pragma unroll
  for (int j = 0; j < 8; ++j) {
    int c = tc * 8 + j;
    float pb = proj_b[c];
    float4 vv;
    vv.x = acc[0][j] + pb + ori[((size_t)b * 1024 + n0 + tn * 4 + 0) * 128 + c];
    vv.y = acc[1][j] + pb + ori[((size_t)b * 1024 + n0 + tn * 4 + 1) * 128 + c];
    vv.z = acc[2][j] + pb + ori[((size_t)b * 1024 + n0 + tn * 4 + 2) * 128 + c];
    vv.w = acc[3][j] + pb + ori[((size_t)b * 1024 + n0 + tn * 4 + 3) * 128 + c];
    *(float4*)(xv2 + ((size_t)b * 128 + c) * 1024 + n0 + tn * 4) = vv;
  }
}

// K8: conv1d over n (128->128 channels, K=5, pad=2) + residual
__global__ __launch_bounds__(256) void k_conv1d(
    const float* __restrict__ xv2, const float* __restrict__ cw,
    float* __restrict__ xv3) {
  int nt = blockIdx.x, b = blockIdx.y;
  int n0 = nt << 6;
  extern __shared__ float lds[];
  float* xl = lds;                 // [128][68]
  float* wl = lds + 128 * 68;      // [40][129]
  int t = threadIdx.x, oc = t & 127, g = t >> 7;
  const float* xb = xv2 + (size_t)b * 128 * 1024;
  for (int idx = t; idx < 8704; idx += 256) {
    int ic = idx / 68, j = idx - ic * 68;
    int n = n0 + j - 2;
    xl[idx] = (n >= 0 && n < 1024) ? xb[(size_t)ic * 1024 + n] : 0.f;
  }
  float acc[32];
#pragma unroll
  for (int i = 0; i < 32; ++i) acc[i] = 0.f;
  for (int ch = 0; ch < 16; ++ch) {
    __syncthreads();
    for (int idx = t; idx < 5120; idx += 256) {
      int r = idx % 40, o_ = idx / 40;
      wl[r * 129 + o_] = cw[o_ * 640 + ch * 40 + r];
    }
    __syncthreads();
#pragma unroll 1
    for (int icl = 0; icl < 8; ++icl) {
      int ic = (ch << 3) + icl;
      const float* wr = wl + icl * 5 * 129 + oc;
      float w0 = wr[0], w1 = wr[129], w2 = wr[258], w3 = wr[387], w4 = wr[516];
      float xw[36];
      const float4* xr = (const float4*)(xl + ic * 68 + (g << 5));
#pragma unroll
      for (int q2 = 0; q2 < 9; ++q2) {
        float4 vv = xr[q2];
        xw[q2 * 4] = vv.x; xw[q2 * 4 + 1] = vv.y; xw[q2 * 4 + 2] = vv.z; xw[q2 * 4 + 3] = vv.w;
      }
#pragma unroll
      for (int i = 0; i < 32; ++i)
        acc[i] = fmaf(xw[i], w0, fmaf(xw[i + 1], w1, fmaf(xw[i + 2], w2,
                 fmaf(xw[i + 3], w3, fmaf(xw[i + 4], w4, acc[i])))));
    }
  }
  const float* res = xb + (size_t)oc * 1024 + n0 + (g << 5);
  float* outp = xv3 + ((size_t)b * 128 + oc) * 1024 + n0 + (g << 5);
#pragma unroll
  for (int i = 0; i < 32; ++i) outp[i] = res[i] + acc[i];
}

// K9: bilinear 32->96 align_corners=True, f32 out
__global__ __launch_bounds__(256) void k_bilinear(const float* __restrict__ xv3,
                                                  float* __restrict__ out) {
  int idx = blockIdx.x * 256 + threadIdx.x;
  int X = idx % 96;
  int t2 = idx / 96;
  int Y = t2 % 96;
  int bc = t2 / 96;
  const float* src = xv3 + (size_t)bc * 1024;
  const float r = 31.f / 95.f;
  float py = Y * r, px = X * r;
  int y0 = (int)py, x0 = (int)px;
  float wy = py - y0, wx = px - x0;
  int y1 = y0 < 31 ? y0 + 1 : 31, x1 = x0 < 31 ? x0 + 1 : 31;
  float a = src[y0 * 32 + x0], b_ = src[y0 * 32 + x1];
  float c_ = src[y1 * 32 + x0], d_ = src[y1 * 32 + x1];
  float t0 = a * (1.f - wy) + c_ * wy;
  float t1 = b_ * (1.f - wy) + d_ * wy;
  out[idx] = t0 * (1.f - wx) + t1 * wx;
}

extern "C" void kernel_launch(void* const* d_in, const int* in_sizes, int n_in,
                              void* d_out, int out_size, void* d_ws, size_t ws_size,
                              hipStream_t stream) {
  (void)in_sizes; (void)n_in; (void)out_size; (void)ws_size;
  const float* s1    = (const float*)d_in[0];
  const float* o     = (const float*)d_in[1];
  const int*   indx  = (const int*)d_in[2];
  const float* pe_w  = (const float*)d_in[3];
  const float* bn_g  = (const float*)d_in[4];
  const float* bn_b  = (const float*)d_in[5];
  const float* bn_m  = (const float*)d_in[6];
  const float* bn_v  = (const float*)d_in[7];
  const float* lnx_g = (const float*)d_in[8];
  const float* lnx_b = (const float*)d_in[9];
  const float* lny_g = (const float*)d_in[10];
  const float* lny_b = (const float*)d_in[11];
  const float* qkv_w = (const float*)d_in[12];
  const float* qkv_b = (const float*)d_in[13];
  const float* yv_w  = (const float*)d_in[14];
  const float* yv_b  = (const float*)d_in[15];
  const float* proj_w = (const float*)d_in[16];
  const float* proj_b = (const float*)d_in[17];
  const float* c1d_w  = (const float*)d_in[18];

  char* ws = (char*)d_ws;
  // Peak footprint 75,497,472 B:
  // Phase 1: xTh bf16 [ws+0, 37.7MB), ymh bf16 [ws+37.7MB, 75.5MB).
  unsigned short* xTh = (unsigned short*)ws;
  unsigned short* ymh = (unsigned short*)(ws + 37748736);
  // Phase 2 (xTh dead after k_conv_pe): region A = [ws+0, 37.7MB)
  float* ori  = (float*)ws;
  float* sn   = (float*)(ws + 8388608);
  float* ofl  = (float*)(ws + 16777216);
  float* attb = (float*)(ws + 25165824);
  // Phase 3 (ymh dead after k_pool9): region B = [ws+37.7MB, 75.5MB)
  float* qkvb  = (float*)(ws + 37748736);
  float* yvbuf = (float*)(ws + 62914560);
  float* xv2   = (float*)(ws + 37748736);   // alias qkvb (dead after k_attn)
  float* xv3   = (float*)(ws + 46137344);

  hipLaunchKernelGGL(k_transpose, dim3(96, 16), dim3(256), 0, stream, s1, xTh);
  hipLaunchKernelGGL(k_conv_pe, dim3(36, 16), dim3(256), 80192, stream,
                     xTh, pe_w, bn_g, bn_b, bn_m, bn_v, indx, ymh);
  hipLaunchKernelGGL(k_pool9, dim3(64, 16), dim3(256), 0, stream, ymh, ori);
  hipLaunchKernelGGL(k_poolo_ln, dim3(32, 16), dim3(256), 0, stream, o, lnx_g, lnx_b, ofl);
  hipLaunchKernelGGL(k_ln, dim3(1024, 16), dim3(128), 0, stream, ori, lny_g, lny_b, sn);
  hipLaunchKernelGGL(k_gemm, dim3(256, 6), dim3(256), 0, stream, ofl, qkv_w, qkv_b, qkvb, 384);
  hipLaunchKernelGGL(k_gemm, dim3(256, 2), dim3(256), 0, stream, sn, yv_w, yv_b, yvbuf, 128);
  hipLaunchKernelGGL(k_attn, dim3(16, 4, 16), dim3(256), 0, stream, qkvb, yvbuf, attb);
  hipLaunchKernelGGL(k_proj, dim3(16, 16), dim3(256), 0, stream, attb, proj_w, proj_b, ori, xv2);
  hipLaunchKernelGGL(k_conv1d, dim3(16, 16), dim3(256), 55456, stream, xv2, c1d_w, xv3);
  hipLaunchKernelGGL(k_bilinear, dim3(73728), dim3(256), 0, stream, xv3, (float*)d_out);
}

// Round 5
// 678.294 us; speedup vs baseline: 1.4560x; 1.2396x over previous
//
#include <hip/hip_runtime.h>

#define FEAT 18432

typedef __attribute__((ext_vector_type(8))) short short8;
typedef __attribute__((ext_vector_type(4))) float f32x4;

__device__ __forceinline__ float b2f(unsigned short s) {
  union { unsigned int u; float f; } v; v.u = ((unsigned int)s) << 16; return v.f;
}
__device__ __forceinline__ unsigned short f2bf(float x) {
  union { float f; unsigned int u; } v; v.f = x;
  unsigned int u = v.u;
  unsigned int r = (u + 0x7FFFu + ((u >> 16) & 1u)) >> 16;
  return (unsigned short)r;
}

// K0: s1[b][c][96][96] (f32) -> xT[b][patch=gh*8+gw][f=(p1*12+p2)*128+c] (bf16 staging)
__global__ __launch_bounds__(256) void k_transpose(const float* __restrict__ s1,
                                                   unsigned short* __restrict__ xT) {
  int H = blockIdx.x, b = blockIdx.y;
  int gh = H / 12, p1 = H % 12;
  __shared__ float lds[128][97];
  const float* src = s1 + ((size_t)b * 128) * 9216 + (size_t)H * 96;
  for (int idx = threadIdx.x; idx < 12288; idx += 256) {
    int c = idx / 96, w = idx - c * 96;
    lds[c][w] = src[(size_t)c * 9216 + w];
  }
  __syncthreads();
  unsigned short* dst = xT + (size_t)b * 64 * FEAT + (size_t)(gh * 8) * FEAT + (p1 * 12) * 128;
  for (int idx = threadIdx.x; idx < 6144; idx += 256) {
    int c2 = idx & 63, rem = idx >> 6;      // rem = gw*12+p2 in [0,96)
    unsigned int lo = f2bf(lds[c2 * 2][rem]);
    unsigned int hi = f2bf(lds[c2 * 2 + 1][rem]);
    int gw = rem / 12, p2 = rem - gw * 12;
    *(unsigned int*)(dst + (size_t)gw * FEAT + p2 * 128 + c2 * 2) = lo | (hi << 16);
  }
}

// K1 (MFMA): conv1d over f as GEMM M=64(oc) x N=18432(f) x K=320(kk*64+ic)
// + BN(eval) + ReLU + selective square. 16x16x32 bf16 MFMA.
__global__ __launch_bounds__(256) void k_conv_pe(
    const unsigned short* __restrict__ xT, const float* __restrict__ pe_w,
    const float* __restrict__ bn_g, const float* __restrict__ bn_b,
    const float* __restrict__ bn_m, const float* __restrict__ bn_v,
    const int* __restrict__ indexp, unsigned short* __restrict__ ym) {
  extern __shared__ char smem[];
  unsigned short* Wl = (unsigned short*)smem;            // 64*328*2 = 41984 B
  unsigned short* xl = (unsigned short*)(smem + 41984);  // 260*72*2 = 37440 B
  float* scf = (float*)(smem + 79424);                   // 64 f32
  float* shf = (float*)(smem + 79680);                   // 64 f32
  int*   sli = (int*)(smem + 79936);                     // 64 int
  int t = threadIdx.x;
  int b = blockIdx.y;
  int blk_f0 = blockIdx.x << 9;                          // 512 f per block

  for (int idx = t; idx < 20480; idx += 256) {
    int oc = idx / 320;
    int c = idx - oc * 320;
    Wl[oc * 328 + c] = f2bf(pe_w[(oc * 64 + (c & 63)) * 5 + (c >> 6)]);
  }
  if (t < 64) {
    float sc = bn_g[t] * rsqrtf(bn_v[t] + 1e-5f);
    scf[t] = sc;
    shf[t] = bn_b[t] - bn_m[t] * sc;
    int i0 = indexp[0] / 12 * 8 + indexp[1] / 12;
    int i1 = indexp[2] / 12 * 8 + indexp[3] / 12;
    int i2 = indexp[4] / 12 * 8 + indexp[5] / 12;
    int i3 = indexp[6] / 12 * 8 + indexp[7] / 12;
    sli[t] = (t == i0 || t == i1 || t == i2 || t == i3) ? 1 : 0;
  }

  const unsigned short* xb = xT + (size_t)b * 64 * FEAT;
  int lane = t & 63, w = t >> 6;
  int n16 = lane & 15, q = lane >> 4;

  int aB0 = n16 * 328 + q * 8;
  int bB0 = (w * 64 + n16) * 72 + q * 8;

  for (int wnd = 0; wnd < 2; ++wnd) {
    int F0 = blk_f0 + (wnd << 8);
    __syncthreads();
    for (int idx = t; idx < 16640; idx += 256) {
      int ic = idx / 260, fl = idx - ic * 260;
      int f = F0 - 2 + fl;
      unsigned short v = 0;
      if (f >= 0 && f < FEAT) v = xb[(size_t)ic * FEAT + f];
      xl[fl * 72 + ic] = v;
    }
    __syncthreads();

    f32x4 acc[4][4];
#pragma unroll
    for (int mt = 0; mt < 4; ++mt)
#pragma unroll
      for (int nt = 0; nt < 4; ++nt) acc[mt][nt] = (f32x4){0.f, 0.f, 0.f, 0.f};

#pragma unroll
    for (int kk = 0; kk < 5; ++kk) {
#pragma unroll
      for (int ih = 0; ih < 2; ++ih) {
        int ao = kk * 64 + ih * 32;
        int bo = kk * 72 + ih * 32;
        short8 a0 = *(const short8*)(Wl + aB0 + ao);
        short8 a1 = *(const short8*)(Wl + aB0 + 16 * 328 + ao);
        short8 a2 = *(const short8*)(Wl + aB0 + 32 * 328 + ao);
        short8 a3 = *(const short8*)(Wl + aB0 + 48 * 328 + ao);
        short8 b0 = *(const short8*)(xl + bB0 + bo);
        short8 b1 = *(const short8*)(xl + bB0 + 16 * 72 + bo);
        short8 b2 = *(const short8*)(xl + bB0 + 32 * 72 + bo);
        short8 b3 = *(const short8*)(xl + bB0 + 48 * 72 + bo);
        acc[0][0] = __builtin_amdgcn_mfma_f32_16x16x32_bf16(a0, b0, acc[0][0], 0, 0, 0);
        acc[0][1] = __builtin_amdgcn_mfma_f32_16x16x32_bf16(a0, b1, acc[0][1], 0, 0, 0);
        acc[0][2] = __builtin_amdgcn_mfma_f32_16x16x32_bf16(a0, b2, acc[0][2], 0, 0, 0);
        acc[0][3] = __builtin_amdgcn_mfma_f32_16x16x32_bf16(a0, b3, acc[0][3], 0, 0, 0);
        acc[1][0] = __builtin_amdgcn_mfma_f32_16x16x32_bf16(a1, b0, acc[1][0], 0, 0, 0);
        acc[1][1] = __builtin_amdgcn_mfma_f32_16x16x32_bf16(a1, b1, acc[1][1], 0, 0, 0);
        acc[1][2] = __builtin_amdgcn_mfma_f32_16x16x32_bf16(a1, b2, acc[1][2], 0, 0, 0);
        acc[1][3] = __builtin_amdgcn_mfma_f32_16x16x32_bf16(a1, b3, acc[1][3], 0, 0, 0);
        acc[2][0] = __builtin_amdgcn_mfma_f32_16x16x32_bf16(a2, b0, acc[2][0], 0, 0, 0);
        acc[2][1] = __builtin_amdgcn_mfma_f32_16x16x32_bf16(a2, b1, acc[2][1], 0, 0, 0);
        acc[2][2] = __builtin_amdgcn_mfma_f32_16x16x32_bf16(a2, b2, acc[2][2], 0, 0, 0);
        acc[2][3] = __builtin_amdgcn_mfma_f32_16x16x32_bf16(a2, b3, acc[2][3], 0, 0, 0);
        acc[3][0] = __builtin_amdgcn_mfma_f32_16x16x32_bf16(a3, b0, acc[3][0], 0, 0, 0);
        acc[3][1] = __builtin_amdgcn_mfma_f32_16x16x32_bf16(a3, b1, acc[3][1], 0, 0, 0);
        acc[3][2] = __builtin_amdgcn_mfma_f32_16x16x32_bf16(a3, b2, acc[3][2], 0, 0, 0);
        acc[3][3] = __builtin_amdgcn_mfma_f32_16x16x32_bf16(a3, b3, acc[3][3], 0, 0, 0);
      }
    }

#pragma unroll
    for (int mt = 0; mt < 4; ++mt) {
#pragma unroll
      for (int i = 0; i < 4; ++i) {
        int oc = mt * 16 + q * 4 + i;
        float sc = scf[oc], sh = shf[oc];
        bool sel = sli[oc] != 0;
        unsigned short* yo = ym + ((size_t)b * 64 + oc) * FEAT + F0 + w * 64 + n16;
#pragma unroll
        for (int nt = 0; nt < 4; ++nt) {
          float y = fmaf(acc[mt][nt][i], sc, sh);
          y = fmaxf(y, 0.f);
          if (!sel) y *= y;
          yo[nt * 16] = f2bf(y);
        }
      }
    }
  }
}

// K2: 3x3 avg pool 96->32 in patch layout -> ori[b][n][c] (f32)
__global__ __launch_bounds__(256) void k_pool9(const unsigned short* __restrict__ ym,
                                               float* __restrict__ ori) {
  int oc = blockIdx.x, b = blockIdx.y;
  const unsigned short* src = ym + ((size_t)b * 64 + oc) * FEAT;
  int oh0 = (oc >> 3) << 2, ow0 = (oc & 7) << 2;
  for (int idx = threadIdx.x; idx < 2048; idx += 256) {
    int c = idx & 127, nl = idx >> 7;
    int pg1 = nl >> 2, pg2 = nl & 3;
    int pbase = (pg1 * 36 + pg2 * 3) * 128 + c;
    float s = 0.f;
#pragma unroll
    for (int dy = 0; dy < 3; ++dy)
#pragma unroll
      for (int dx = 0; dx < 3; ++dx)
        s += b2f(src[pbase + (dy * 12 + dx) * 128]);
    int n = (oh0 + pg1) * 32 + ow0 + pg2;
    ori[((size_t)b * 1024 + n) * 128 + c] = s * (1.f / 9.f);
  }
}

// K3: 2x2 avg pool of o (f32, 64->32) + LayerNorm over C -> ofl[b][n][c]
__global__ __launch_bounds__(256) void k_poolo_ln(
    const float* __restrict__ o, const float* __restrict__ lng,
    const float* __restrict__ lnb, float* __restrict__ ofl) {
  int y = blockIdx.x, b = blockIdx.y;
  __shared__ float pl[128 * 33];
  int t = threadIdx.x;
  for (int idx = t; idx < 4096; idx += 256) {
    int xo = idx & 31, c = idx >> 5;
    const float* p = o + (((size_t)b * 128 + c) * 64 + 2 * y) * 64 + 2 * xo;
    float2 a = *(const float2*)p;
    float2 d = *(const float2*)(p + 64);
    pl[c * 33 + xo] = 0.25f * (a.x + a.y + d.x + d.y);
  }
  __syncthreads();
  int xo = t >> 3, l8 = t & 7;
  float v[16]; float s = 0.f, q = 0.f;
#pragma unroll
  for (int i = 0; i < 16; ++i) {
    float x = pl[(l8 * 16 + i) * 33 + xo];
    v[i] = x; s += x; q += x * x;
  }
#pragma unroll
  for (int off = 1; off < 8; off <<= 1) {
    s += __shfl_xor(s, off, 8);
    q += __shfl_xor(q, off, 8);
  }
  float mean = s * (1.f / 128.f);
  float var = q * (1.f / 128.f) - mean * mean;
  float inv = rsqrtf(var + 1e-5f);
  float* dst = ofl + ((size_t)b * 1024 + y * 32 + xo) * 128 + l8 * 16;
#pragma unroll
  for (int i = 0; i < 16; ++i)
    dst[i] = (v[i] - mean) * inv * lng[l8 * 16 + i] + lnb[l8 * 16 + i];
}

// K4: LayerNorm over C of ori -> sn
__global__ __launch_bounds__(128) void k_ln(
    const float* __restrict__ src, const float* __restrict__ lng,
    const float* __restrict__ lnb, float* __restrict__ dst) {
  int n = blockIdx.x, b = blockIdx.y;
  size_t base = ((size_t)b * 1024 + n) * 128;
  int c = threadIdx.x;
  float v = src[base + c];
  float s = v, q = v * v;
#pragma unroll
  for (int off = 32; off > 0; off >>= 1) {
    s += __shfl_xor(s, off, 64);
    q += __shfl_xor(q, off, 64);
  }
  __shared__ float red[4];
  if ((c & 63) == 0) { red[(c >> 6) * 2] = s; red[(c >> 6) * 2 + 1] = q; }
  __syncthreads();
  s = red[0] + red[2]; q = red[1] + red[3];
  float mean = s * (1.f / 128.f);
  float var = q * (1.f / 128.f) - mean * mean;
  float inv = rsqrtf(var + 1e-5f);
  dst[base + c] = (v - mean) * inv * lng[c] + lnb[c];
}

// K5: out[M][Ncols] = A[M][128] @ W[Ncols][128]^T + bias
__global__ __launch_bounds__(256) void k_gemm(
    const float* __restrict__ A, const float* __restrict__ W,
    const float* __restrict__ bias, float* __restrict__ out, int Ncols) {
  int mt = blockIdx.x, ct = blockIdx.y;
  int m0 = mt << 6, c0 = ct << 6;
  __shared__ float Al[64 * 67], Wl[64 * 67];
  int t = threadIdx.x, tm = t & 15, tc = t >> 4;
  float acc[4][4];
#pragma unroll
  for (int i = 0; i < 4; ++i)
#pragma unroll
    for (int j = 0; j < 4; ++j) acc[i][j] = 0.f;
  for (int kc = 0; kc < 2; ++kc) {
    __syncthreads();
    for (int idx = t; idx < 4096; idx += 256) {
      int r = idx >> 6, kk = idx & 63;
      Al[r * 67 + kk] = A[(size_t)(m0 + r) * 128 + kc * 64 + kk];
      Wl[r * 67 + kk] = W[(size_t)(c0 + r) * 128 + kc * 64 + kk];
    }
    __syncthreads();
    for (int kk = 0; kk < 64; ++kk) {
      float a[4], w[4];
#pragma unroll
      for (int i = 0; i < 4; ++i) a[i] = Al[(tm * 4 + i) * 67 + kk];
#pragma unroll
      for (int j = 0; j < 4; ++j) w[j] = Wl[(tc * 4 + j) * 67 + kk];
#pragma unroll
      for (int i = 0; i < 4; ++i)
#pragma unroll
        for (int j = 0; j < 4; ++j) acc[i][j] = fmaf(a[i], w[j], acc[i][j]);
    }
  }
#pragma unroll
  for (int i = 0; i < 4; ++i) {
    float4 vv;
    vv.x = acc[i][0] + bias[c0 + tc * 4 + 0];
    vv.y = acc[i][1] + bias[c0 + tc * 4 + 1];
    vv.z = acc[i][2] + bias[c0 + tc * 4 + 2];
    vv.w = acc[i][3] + bias[c0 + tc * 4 + 3];
    *(float4*)(out + (size_t)(m0 + tm * 4 + i) * Ncols + c0 + tc * 4) = vv;
  }
}

// K6 (MFMA): flash attention per (b,h,q-tile of 128): att = v + softmax(qk^T/sqrt(32)) @ yv
// 4 waves x 32 q-rows. QK^T and PV via mfma_f32_16x16x32_bf16; P round-trips LDS.
__global__ __launch_bounds__(256) void k_attn(const float* __restrict__ qkv,
                                              const float* __restrict__ yvb,
                                              float* __restrict__ att) {
  int qt = blockIdx.x, h = blockIdx.y, b = blockIdx.z;
  __shared__ unsigned short Qs[128 * 40];   // [qlocal][d], pad 40
  __shared__ unsigned short Ks[64 * 40];    // [keylocal][d], pad 40
  __shared__ unsigned short Vt[32 * 72];    // [d][keylocal], pad 72
  __shared__ unsigned short Pw[4 * 32 * 72];// per-wave [qlocal32][key64], pad 72
  int t = threadIdx.x;
  int lane = t & 63, w = t >> 6;
  int quad = lane >> 4, l16 = lane & 15;
  const float* qbase = qkv + (size_t)b * 1024 * 384;
  const float* vbase = yvb + (size_t)b * 1024 * 128;
  int q0 = qt << 7;
  int hd = h * 32;

  for (int idx = t; idx < 4096; idx += 256) {
    int d = idx & 31, r = idx >> 5;
    Qs[r * 40 + d] = f2bf(qbase[(size_t)(q0 + r) * 384 + hd + d]);
  }

  f32x4 O[2][2];
  float mi[2][4], li[2][4];
#pragma unroll
  for (int mt = 0; mt < 2; ++mt) {
    O[mt][0] = (f32x4){0.f, 0.f, 0.f, 0.f};
    O[mt][1] = (f32x4){0.f, 0.f, 0.f, 0.f};
#pragma unroll
    for (int i = 0; i < 4; ++i) { mi[mt][i] = -1e30f; li[mt][i] = 0.f; }
  }
  unsigned short* Pme = Pw + w * (32 * 72);
  const float scl = 0.17677669529663688f;

  for (int c = 0; c < 16; ++c) {
    __syncthreads();
    int kn0 = c << 6;
    for (int idx = t; idx < 2048; idx += 256) {
      int d = idx & 31, r = idx >> 5;
      Ks[r * 40 + d] = f2bf(qbase[(size_t)(kn0 + r) * 384 + 128 + hd + d]);
      Vt[d * 72 + r] = f2bf(vbase[(size_t)(kn0 + r) * 128 + hd + d]);
    }
    __syncthreads();

    // QK^T: S[mt][nt] C-layout: row=q(quad*4+reg), col=key(l16)
    short8 aq0 = *(const short8*)(Qs + (w * 32 + l16) * 40 + quad * 8);
    short8 aq1 = *(const short8*)(Qs + (w * 32 + 16 + l16) * 40 + quad * 8);
    f32x4 S[2][4];
#pragma unroll
    for (int mt = 0; mt < 2; ++mt)
#pragma unroll
      for (int nt = 0; nt < 4; ++nt) S[mt][nt] = (f32x4){0.f, 0.f, 0.f, 0.f};
#pragma unroll
    for (int nt = 0; nt < 4; ++nt) {
      short8 bk = *(const short8*)(Ks + (nt * 16 + l16) * 40 + quad * 8);
      S[0][nt] = __builtin_amdgcn_mfma_f32_16x16x32_bf16(aq0, bk, S[0][nt], 0, 0, 0);
      S[1][nt] = __builtin_amdgcn_mfma_f32_16x16x32_bf16(aq1, bk, S[1][nt], 0, 0, 0);
    }

    // online softmax per mtile; write P (bf16) to per-wave LDS
#pragma unroll
    for (int mt = 0; mt < 2; ++mt) {
#pragma unroll
      for (int reg = 0; reg < 4; ++reg) {
        float s0 = S[mt][0][reg] * scl, s1 = S[mt][1][reg] * scl;
        float s2 = S[mt][2][reg] * scl, s3 = S[mt][3][reg] * scl;
        float rm = fmaxf(fmaxf(s0, s1), fmaxf(s2, s3));
        rm = fmaxf(rm, __shfl_xor(rm, 1));
        rm = fmaxf(rm, __shfl_xor(rm, 2));
        rm = fmaxf(rm, __shfl_xor(rm, 4));
        rm = fmaxf(rm, __shfl_xor(rm, 8));
        float nm = fmaxf(mi[mt][reg], rm);
        float alpha = __expf(mi[mt][reg] - nm);
        mi[mt][reg] = nm;
        float p0 = __expf(s0 - nm), p1 = __expf(s1 - nm);
        float p2 = __expf(s2 - nm), p3 = __expf(s3 - nm);
        int pr = (mt * 16 + quad * 4 + reg) * 72 + l16;
        Pme[pr]      = f2bf(p0);
        Pme[pr + 16] = f2bf(p1);
        Pme[pr + 32] = f2bf(p2);
        Pme[pr + 48] = f2bf(p3);
        float ps = (p0 + p1) + (p2 + p3);
        ps += __shfl_xor(ps, 1);
        ps += __shfl_xor(ps, 2);
        ps += __shfl_xor(ps, 4);
        ps += __shfl_xor(ps, 8);
        li[mt][reg] = li[mt][reg] * alpha + ps;
        O[mt][0][reg] *= alpha;
        O[mt][1][reg] *= alpha;
      }
    }

    // PV: O[mt][nt] += P[mt] @ Vt[nt]
#pragma unroll
    for (int kc = 0; kc < 2; ++kc) {
      short8 bv0 = *(const short8*)(Vt + l16 * 72 + kc * 32 + quad * 8);
      short8 bv1 = *(const short8*)(Vt + (16 + l16) * 72 + kc * 32 + quad * 8);
      short8 ap0 = *(const short8*)(Pme + l16 * 72 + kc * 32 + quad * 8);
      short8 ap1 = *(const short8*)(Pme + (16 + l16) * 72 + kc * 32 + quad * 8);
      O[0][0] = __builtin_amdgcn_mfma_f32_16x16x32_bf16(ap0, bv0, O[0][0], 0, 0, 0);
      O[0][1] = __builtin_amdgcn_mfma_f32_16x16x32_bf16(ap0, bv1, O[0][1], 0, 0, 0);
      O[1][0] = __builtin_amdgcn_mfma_f32_16x16x32_bf16(ap1, bv0, O[1][0], 0, 0, 0);
      O[1][1] = __builtin_amdgcn_mfma_f32_16x16x32_bf16(ap1, bv1, O[1][1], 0, 0, 0);
    }
  }

  // epilogue: O/li + v residual
#pragma unroll
  for (int mt = 0; mt < 2; ++mt) {
#pragma unroll
    for (int reg = 0; reg < 4; ++reg) {
      int n = q0 + w * 32 + mt * 16 + quad * 4 + reg;
      float inv = 1.f / li[mt][reg];
#pragma unroll
      for (int nt = 0; nt < 2; ++nt) {
        int dd = hd + nt * 16 + l16;
        float val = O[mt][nt][reg] * inv + qbase[(size_t)n * 384 + 256 + dd];
        att[((size_t)b * 1024 + n) * 128 + dd] = val;
      }
    }
  }
}

// K7: proj GEMM + bias + ori residual, write transposed xv2[b][c][n]
__global__ __launch_bounds__(256) void k_proj(
    const float* __restrict__ att, const float* __restrict__ proj_w,
    const float* __restrict__ proj_b, const float* __restrict__ ori,
    float* __restrict__ xv2) {
  int nt = blockIdx.x, b = blockIdx.y;
  int n0 = nt << 6;
  __shared__ float Al[64 * 67], Wl[128 * 67];
  int t = threadIdx.x, tn = t & 15, tc = t >> 4;
  float acc[4][8];
#pragma unroll
  for (int i = 0; i < 4; ++i)
#pragma unroll
    for (int j = 0; j < 8; ++j) acc[i][j] = 0.f;
  const float* Ab = att + ((size_t)b * 1024 + n0) * 128;
  for (int kc = 0; kc < 2; ++kc) {
    __syncthreads();
    for (int idx = t; idx < 4096; idx += 256) {
      int r = idx >> 6, kk = idx & 63;
      Al[r * 67 + kk] = Ab[(size_t)r * 128 + kc * 64 + kk];
    }
    for (int idx = t; idx < 8192; idx += 256) {
      int r = idx >> 6, kk = idx & 63;
      Wl[r * 67 + kk] = proj_w[(size_t)r * 128 + kc * 64 + kk];
    }
    __syncthreads();
    for (int kk = 0; kk < 64; ++kk) {
      float a[4], w[8];
#pragma unroll
      for (int i = 0; i < 4; ++i) a[i] = Al[(tn * 4 + i) * 67 + kk];
#pragma unroll
      for (int j = 0; j < 8; ++j) w[j] = Wl[(tc * 8 + j) * 67 + kk];
#pragma unroll
      for (int i = 0; i < 4; ++i)
#pragma unroll
        for (int j = 0; j < 8; ++j) acc[i][j] = fmaf(a[i], w[j], acc[i][j]);
    }
  }
#pragma unroll
  for (int j = 0; j < 8; ++j) {
    int c = tc * 8 + j;
    float pb = proj_b[c];
    float4 vv;
    vv.x = acc[0][j] + pb + ori[((size_t)b * 1024 + n0 + tn * 4 + 0) * 128 + c];
    vv.y = acc[1][j] + pb + ori[((size_t)b * 1024 + n0 + tn * 4 + 1) * 128 + c];
    vv.z = acc[2][j] + pb + ori[((size_t)b * 1024 + n0 + tn * 4 + 2) * 128 + c];
    vv.w = acc[3][j] + pb + ori[((size_t)b * 1024 + n0 + tn * 4 + 3) * 128 + c];
    *(float4*)(xv2 + ((size_t)b * 128 + c) * 1024 + n0 + tn * 4) = vv;
  }
}

// K8: conv1d over n (128->128 channels, K=5, pad=2) + residual
__global__ __launch_bounds__(256) void k_conv1d(
    const float* __restrict__ xv2, const float* __restrict__ cw,
    float* __restrict__ xv3) {
  int nt = blockIdx.x, b = blockIdx.y;
  int n0 = nt << 6;
  extern __shared__ float lds[];
  float* xl = lds;                 // [128][68]
  float* wl = lds + 128 * 68;      // [40][129]
  int t = threadIdx.x, oc = t & 127, g = t >> 7;
  const float* xb = xv2 + (size_t)b * 128 * 1024;
  for (int idx = t; idx < 8704; idx += 256) {
    int ic = idx / 68, j = idx - ic * 68;
    int n = n0 + j - 2;
    xl[idx] = (n >= 0 && n < 1024) ? xb[(size_t)ic * 1024 + n] : 0.f;
  }
  float acc[32];
#pragma unroll
  for (int i = 0; i < 32; ++i) acc[i] = 0.f;
  for (int ch = 0; ch < 16; ++ch) {
    __syncthreads();
    for (int idx = t; idx < 5120; idx += 256) {
      int r = idx % 40, o_ = idx / 40;
      wl[r * 129 + o_] = cw[o_ * 640 + ch * 40 + r];
    }
    __syncthreads();
#pragma unroll 1
    for (int icl = 0; icl < 8; ++icl) {
      int ic = (ch << 3) + icl;
      const float* wr = wl + icl * 5 * 129 + oc;
      float w0 = wr[0], w1 = wr[129], w2 = wr[258], w3 = wr[387], w4 = wr[516];
      float xw[36];
      const float4* xr = (const float4*)(xl + ic * 68 + (g << 5));
#pragma unroll
      for (int q2 = 0; q2 < 9; ++q2) {
        float4 vv = xr[q2];
        xw[q2 * 4] = vv.x; xw[q2 * 4 + 1] = vv.y; xw[q2 * 4 + 2] = vv.z; xw[q2 * 4 + 3] = vv.w;
      }
#pragma unroll
      for (int i = 0; i < 32; ++i)
        acc[i] = fmaf(xw[i], w0, fmaf(xw[i + 1], w1, fmaf(xw[i + 2], w2,
                 fmaf(xw[i + 3], w3, fmaf(xw[i + 4], w4, acc[i])))));
    }
  }
  const float* res = xb + (size_t)oc * 1024 + n0 + (g << 5);
  float* outp = xv3 + ((size_t)b * 128 + oc) * 1024 + n0 + (g << 5);
#pragma unroll
  for (int i = 0; i < 32; ++i) outp[i] = res[i] + acc[i];
}

// K9: bilinear 32->96 align_corners=True, f32 out
__global__ __launch_bounds__(256) void k_bilinear(const float* __restrict__ xv3,
                                                  float* __restrict__ out) {
  int idx = blockIdx.x * 256 + threadIdx.x;
  int X = idx % 96;
  int t2 = idx / 96;
  int Y = t2 % 96;
  int bc = t2 / 96;
  const float* src = xv3 + (size_t)bc * 1024;
  const float r = 31.f / 95.f;
  float py = Y * r, px = X * r;
  int y0 = (int)py, x0 = (int)px;
  float wy = py - y0, wx = px - x0;
  int y1 = y0 < 31 ? y0 + 1 : 31, x1 = x0 < 31 ? x0 + 1 : 31;
  float a = src[y0 * 32 + x0], b_ = src[y0 * 32 + x1];
  float c_ = src[y1 * 32 + x0], d_ = src[y1 * 32 + x1];
  float t0 = a * (1.f - wy) + c_ * wy;
  float t1 = b_ * (1.f - wy) + d_ * wy;
  out[idx] = t0 * (1.f - wx) + t1 * wx;
}

extern "C" void kernel_launch(void* const* d_in, const int* in_sizes, int n_in,
                              void* d_out, int out_size, void* d_ws, size_t ws_size,
                              hipStream_t stream) {
  (void)in_sizes; (void)n_in; (void)out_size; (void)ws_size;
  const float* s1    = (const float*)d_in[0];
  const float* o     = (const float*)d_in[1];
  const int*   indx  = (const int*)d_in[2];
  const float* pe_w  = (const float*)d_in[3];
  const float* bn_g  = (const float*)d_in[4];
  const float* bn_b  = (const float*)d_in[5];
  const float* bn_m  = (const float*)d_in[6];
  const float* bn_v  = (const float*)d_in[7];
  const float* lnx_g = (const float*)d_in[8];
  const float* lnx_b = (const float*)d_in[9];
  const float* lny_g = (const float*)d_in[10];
  const float* lny_b = (const float*)d_in[11];
  const float* qkv_w = (const float*)d_in[12];
  const float* qkv_b = (const float*)d_in[13];
  const float* yv_w  = (const float*)d_in[14];
  const float* yv_b  = (const float*)d_in[15];
  const float* proj_w = (const float*)d_in[16];
  const float* proj_b = (const float*)d_in[17];
  const float* c1d_w  = (const float*)d_in[18];

  char* ws = (char*)d_ws;
  // Peak footprint 75,497,472 B:
  // Phase 1: xTh bf16 [ws+0, 37.7MB), ymh bf16 [ws+37.7MB, 75.5MB).
  unsigned short* xTh = (unsigned short*)ws;
  unsigned short* ymh = (unsigned short*)(ws + 37748736);
  // Phase 2 (xTh dead after k_conv_pe): region A = [ws+0, 37.7MB)
  float* ori  = (float*)ws;
  float* sn   = (float*)(ws + 8388608);
  float* ofl  = (float*)(ws + 16777216);
  float* attb = (float*)(ws + 25165824);
  // Phase 3 (ymh dead after k_pool9): region B = [ws+37.7MB, 75.5MB)
  float* qkvb  = (float*)(ws + 37748736);
  float* yvbuf = (float*)(ws + 62914560);
  float* xv2   = (float*)(ws + 37748736);   // alias qkvb (dead after k_attn)
  float* xv3   = (float*)(ws + 46137344);

  hipLaunchKernelGGL(k_transpose, dim3(96, 16), dim3(256), 0, stream, s1, xTh);
  hipLaunchKernelGGL(k_conv_pe, dim3(36, 16), dim3(256), 80192, stream,
                     xTh, pe_w, bn_g, bn_b, bn_m, bn_v, indx, ymh);
  hipLaunchKernelGGL(k_pool9, dim3(64, 16), dim3(256), 0, stream, ymh, ori);
  hipLaunchKernelGGL(k_poolo_ln, dim3(32, 16), dim3(256), 0, stream, o, lnx_g, lnx_b, ofl);
  hipLaunchKernelGGL(k_ln, dim3(1024, 16), dim3(128), 0, stream, ori, lny_g, lny_b, sn);
  hipLaunchKernelGGL(k_gemm, dim3(256, 6), dim3(256), 0, stream, ofl, qkv_w, qkv_b, qkvb, 384);
  hipLaunchKernelGGL(k_gemm, dim3(256, 2), dim3(256), 0, stream, sn, yv_w, yv_b, yvbuf, 128);
  hipLaunchKernelGGL(k_attn, dim3(8, 4, 16), dim3(256), 0, stream, qkvb, yvbuf, attb);
  hipLaunchKernelGGL(k_proj, dim3(16, 16), dim3(256), 0, stream, attb, proj_w, proj_b, ori, xv2);
  hipLaunchKernelGGL(k_conv1d, dim3(16, 16), dim3(256), 55456, stream, xv2, c1d_w, xv3);
  hipLaunchKernelGGL(k_bilinear, dim3(73728), dim3(256), 0, stream, xv3, (float*)d_out);
}